// Round 1
// baseline (13170.819 us; speedup 1.0000x reference)
//
#include <hip/hip_runtime.h>
#include <stdint.h>

// Problem constants
#define SEQL 512
#define BATCH 64
#define EMB 300
#define EMBP 320          // E padded to multiple of 32
#define HID 1024
#define NWG 64            // workgroups; each owns 16 hidden units (64 gate cols)
#define UNITS 16
#define NKC 42            // K-chunks of 32: 32 (V over H=1024) + 10 (U over EP=320)
#define NKCW 11           // K-chunk slots per wave (42 split round-robin over 4 waves)

typedef __attribute__((ext_vector_type(8))) short short8;
typedef __attribute__((ext_vector_type(4))) float f32x4;

union Frag { short8 v; ushort u[8]; uint uu[4]; };

__device__ __forceinline__ ushort f2bf(float f){
  union { float f; uint u; } c; c.f = f;
  return (ushort)((c.u + 0x7fffu + ((c.u >> 16) & 1u)) >> 16);   // RNE
}

struct Params {
  const ushort* xbf;   // [SEQL][BATCH][EMBP] bf16 embeddings
  ushort* hbuf;        // [2][BATCH][HID] bf16 double-buffered h
  float*  hfinal;      // [BATCH][HID] f32 final h
  int*    flags;       // [NWG] monotonic step counters
  const float* V[4];   // V_i,V_f,V_c,V_o  [HID][HID]
  const float* U[4];   // U_i,U_f,U_c,U_o  [EMB][HID]
  const float* bia[4]; // b_i,b_f,b_c,b_o  [HID]
  const float* Wd;     // [HID][3]
  const float* bd;     // [3]
  float* out;          // [BATCH][3]
};

// ---------------- prep: gather embeddings -> bf16, zero h0 and flags ----------------
__global__ void __launch_bounds__(256) prep(const int* __restrict__ text,
                                            const float* __restrict__ tab,
                                            ushort* __restrict__ xbf,
                                            ushort* __restrict__ hbuf,
                                            int* __restrict__ flags){
  const int tid = blockIdx.x * blockDim.x + threadIdx.x;
  const int nth = gridDim.x * blockDim.x;
  uint* hz = (uint*)hbuf;                       // zero hbuf[0] (B*H bf16 = 32768 dwords)
  for (int i = tid; i < BATCH*HID/2; i += nth) hz[i] = 0u;
  if (tid < NWG) flags[tid] = 0;
  const int nch = SEQL*BATCH*(EMBP/8);
  for (int ch = tid; ch < nch; ch += nth){
    const int e8 = ch % (EMBP/8);
    const int sb = ch / (EMBP/8);               // sb = s*BATCH + b  (layout [s][b][e])
    const int b  = sb & (BATCH-1);
    const int s  = sb >> 6;
    const int tok = text[b*SEQL + s];
    union { ushort u[8]; uint4 v; } o;
    #pragma unroll
    for (int j = 0; j < 8; j++){
      const int e = e8*8 + j;
      o.u[j] = f2bf(e < EMB ? tab[(size_t)tok*EMB + e] : 0.f);
    }
    *(uint4*)&xbf[(size_t)sb*EMBP + e8*8] = o.v;
  }
}

// ---------------- persistent LSTM scan ----------------
__global__ void __launch_bounds__(256, 1) lstm_scan(Params p){
  __shared__ float buffer[2][64][68];   // cross-wave partial sums [buf][col][batch(+pad)]
  __shared__ float cst[UNITS][BATCH];   // cell state (f32)
  __shared__ float bias_l[64];          // 4 gates x 16 units

  const int w    = blockIdx.x;
  const int tid  = threadIdx.x;
  const int wave = tid >> 6;
  const int lane = tid & 63;
  const int n0   = w * UNITS;
  const int mrow = lane & 15;           // A row / D col lane index
  const int qk   = ((lane >> 4) & 3) << 2;  // (lane/16)*4 : k sub-offset
  const int colg = n0 + mrow;           // global unit column for B frags

  if (tid < 64) bias_l[tid] = p.bia[tid >> 4][n0 + (tid & 15)];
  for (int i = tid; i < UNITS*BATCH; i += 256) (&cst[0][0])[i] = 0.f;

  // ---- one-time: load V/U slices as bf16 MFMA B-fragments into registers ----
  // B-frag (16x16x32): lane holds B[k][n], n = lane&15, k = kbase + (j>=4)*16 + (lane>>4)*4 + (j&3)
  short8 bfrag[NKCW][4];
  #pragma unroll
  for (int kcl = 0; kcl < NKCW; kcl++){
    const int kc = wave + kcl*4;        // round-robin K chunks across waves
    #pragma unroll
    for (int nt = 0; nt < 4; nt++){     // nt == gate (i,f,c,o)
      Frag fr;
      #pragma unroll
      for (int j = 0; j < 8; j++){
        float v = 0.f;
        if (kc < NKC){
          const bool isv = (kc < 32);
          const float* Wp = isv ? p.V[nt] : p.U[nt];
          const int kbase = isv ? kc*32 : (kc-32)*32;
          const int krow  = kbase + ((j >> 2) << 4) + qk + (j & 3);
          if (isv || krow < EMB) v = Wp[(size_t)krow*HID + colg];
        }
        fr.u[j] = f2bf(v);
      }
      bfrag[kcl][nt] = fr.v;
    }
  }
  __syncthreads();

  for (int t = 0; t < SEQL; t++){
    // ---- barrier: wait until every WG has published h for step t ----
    if (t > 0){
      if (wave == 0){
        for (;;){
          int v = __hip_atomic_load(&p.flags[lane], __ATOMIC_RELAXED, __HIP_MEMORY_SCOPE_AGENT);
          if (__all(v >= t)) break;
          __builtin_amdgcn_s_sleep(2);
        }
      }
      __syncthreads();
      __threadfence();                  // acquire: make remote h stores visible
    }
    const ushort* __restrict__ hcur = p.hbuf + (size_t)(t & 1) * (BATCH*HID);
    const ushort* __restrict__ xt   = p.xbf + (size_t)t * (BATCH*EMBP);

    f32x4 acc[4][4];
    #pragma unroll
    for (int m = 0; m < 4; m++)
      #pragma unroll
      for (int nt = 0; nt < 4; nt++)
        acc[m][nt] = (f32x4){0.f, 0.f, 0.f, 0.f};

    // ---- gates += h @ V  and  += x_t @ U  (K round-robin across waves) ----
    #pragma unroll
    for (int kcl = 0; kcl < NKCW; kcl++){
      const int kc = wave + kcl*4;
      if (kc < NKC){
        const bool isv = (kc < 32);
        const ushort* base = isv ? (hcur + kc*32) : (xt + (kc-32)*32);
        const int ld = isv ? HID : EMBP;
        Frag af[4];
        #pragma unroll
        for (int m = 0; m < 4; m++){
          const ushort* rp = base + (size_t)(m*16 + mrow)*ld + qk;
          uint2 lo = *(const uint2*)rp;        // k .. k+3
          uint2 hi = *(const uint2*)(rp + 16); // k+16 .. k+19
          af[m].uu[0] = lo.x; af[m].uu[1] = lo.y;
          af[m].uu[2] = hi.x; af[m].uu[3] = hi.y;
        }
        #pragma unroll
        for (int m = 0; m < 4; m++)
          #pragma unroll
          for (int nt = 0; nt < 4; nt++)
            acc[m][nt] = __builtin_amdgcn_mfma_f32_16x16x32_bf16(af[m].v, bfrag[kcl][nt], acc[m][nt], 0, 0, 0);
      }
    }

    // ---- cross-wave reduction: buffer[0]=w0+w2, buffer[1]=w1+w3 ----
    const int fq = (lane >> 4) << 2;    // D rows (batch) = fq + reg
    if (wave >= 2){
      #pragma unroll
      for (int m = 0; m < 4; m++)
        #pragma unroll
        for (int nt = 0; nt < 4; nt++)
          *(f32x4*)&buffer[wave-2][nt*16 + mrow][m*16 + fq] = acc[m][nt];
    }
    __syncthreads();
    if (wave < 2){
      #pragma unroll
      for (int m = 0; m < 4; m++)
        #pragma unroll
        for (int nt = 0; nt < 4; nt++){
          f32x4 o = *(f32x4*)&buffer[wave][nt*16 + mrow][m*16 + fq];
          o += acc[m][nt];
          *(f32x4*)&buffer[wave][nt*16 + mrow][m*16 + fq] = o;
        }
    }
    __syncthreads();

    // ---- elementwise LSTM update; publish h_{t+1} ----
    const int eb = tid & 63;            // batch
    const int uq = tid >> 6;            // unit quad
    ushort* __restrict__ hnxt = p.hbuf + (size_t)((t+1) & 1) * (BATCH*HID);
    ushort hout[4];
    #pragma unroll
    for (int rr = 0; rr < 4; rr++){
      const int u = uq*4 + rr;
      float g0 = buffer[0][ 0+u][eb] + buffer[1][ 0+u][eb] + bias_l[ 0+u];
      float g1 = buffer[0][16+u][eb] + buffer[1][16+u][eb] + bias_l[16+u];
      float g2 = buffer[0][32+u][eb] + buffer[1][32+u][eb] + bias_l[32+u];
      float g3 = buffer[0][48+u][eb] + buffer[1][48+u][eb] + bias_l[48+u];
      float ig = 1.f/(1.f + __expf(-g0));
      float fg = 1.f/(1.f + __expf(-g1));
      float gg = 2.f/(1.f + __expf(-2.f*g2)) - 1.f;
      float og = 1.f/(1.f + __expf(-g3));
      float cv = fg * cst[u][eb] + ig * gg;
      cst[u][eb] = cv;
      float hv = og * (2.f/(1.f + __expf(-2.f*cv)) - 1.f);
      hout[rr] = f2bf(hv);
      if (t == SEQL-1) p.hfinal[(size_t)eb*HID + n0 + u] = hv;
    }
    *(uint2*)&hnxt[(size_t)eb*HID + n0 + uq*4] = *(uint2*)hout;
    __threadfence();                    // release our h stores
    __syncthreads();
    if (tid == 0) __hip_atomic_store(&p.flags[w], t+1, __ATOMIC_RELAXED, __HIP_MEMORY_SCOPE_AGENT);
  }

  // ---- dense head: out[w] = h_n[w] @ Wd + bd (one WG per batch row) ----
  if (wave == 0){
    for (;;){
      int v = __hip_atomic_load(&p.flags[lane], __ATOMIC_RELAXED, __HIP_MEMORY_SCOPE_AGENT);
      if (__all(v >= SEQL)) break;
      __builtin_amdgcn_s_sleep(2);
    }
  }
  __syncthreads();
  __threadfence();

  float s0 = 0.f, s1 = 0.f, s2 = 0.f;
  const float* hf = p.hfinal + (size_t)w * HID;
  for (int k = tid; k < HID; k += 256){
    float hv = hf[k];
    s0 = fmaf(hv, p.Wd[k*3+0], s0);
    s1 = fmaf(hv, p.Wd[k*3+1], s1);
    s2 = fmaf(hv, p.Wd[k*3+2], s2);
  }
  float* red = &buffer[0][0][0];
  red[tid*3+0] = s0; red[tid*3+1] = s1; red[tid*3+2] = s2;
  __syncthreads();
  for (int off = 128; off > 0; off >>= 1){
    if (tid < off){
      red[tid*3+0] += red[(tid+off)*3+0];
      red[tid*3+1] += red[(tid+off)*3+1];
      red[tid*3+2] += red[(tid+off)*3+2];
    }
    __syncthreads();
  }
  if (tid < 3) p.out[w*3 + tid] = red[tid] + p.bd[tid];
}

// ---------------- host ----------------
extern "C" void kernel_launch(void* const* d_in, const int* in_sizes, int n_in,
                              void* d_out, int out_size, void* d_ws, size_t ws_size,
                              hipStream_t stream){
  const int*   text = (const int*)d_in[0];
  const float* tab  = (const float*)d_in[1];

  Params p;
  char* ws = (char*)d_ws;
  size_t off = 0;
  p.xbf    = (const ushort*)(ws + off); off += (size_t)SEQL*BATCH*EMBP*2;  // 20,971,520 B
  p.hbuf   = (ushort*)(ws + off);       off += (size_t)2*BATCH*HID*2;      // 262,144 B
  p.hfinal = (float*)(ws + off);        off += (size_t)BATCH*HID*4;        // 262,144 B
  p.flags  = (int*)(ws + off);          off += 256;

  for (int g = 0; g < 4; g++){
    p.U[g]   = (const float*)d_in[2+g];
    p.V[g]   = (const float*)d_in[6+g];
    p.bia[g] = (const float*)d_in[10+g];
  }
  p.Wd  = (const float*)d_in[14];
  p.bd  = (const float*)d_in[15];
  p.out = (float*)d_out;

  prep<<<1024, 256, 0, stream>>>(text, tab, (ushort*)p.xbf, p.hbuf, p.flags);
  lstm_scan<<<NWG, 256, 0, stream>>>(p);
}

// Round 2
// 6504.946 us; speedup vs baseline: 2.0247x; 2.0247x over previous
//
#include <hip/hip_runtime.h>
#include <stdint.h>

// Problem constants
#define SEQL 512
#define BATCH 64
#define EMB 300
#define EMBP 320          // E padded to multiple of 32
#define HID 1024
#define NWG 64            // workgroups; each owns 16 hidden units (64 gate cols)
#define UNITS 16

typedef __attribute__((ext_vector_type(8))) short short8;
typedef __attribute__((ext_vector_type(4))) float f32x4;
typedef __attribute__((ext_vector_type(2))) unsigned int uint2v;

union Frag { short8 v; ushort u[8]; uint uu[4]; };
struct AF { uint2v lo, hi; };

__device__ __forceinline__ ushort f2bf(float f){
  union { float f; uint u; } c; c.f = f;
  return (ushort)((c.u + 0x7fffu + ((c.u >> 16) & 1u)) >> 16);   // RNE
}

struct Params {
  const ushort* xbf;   // [SEQL][BATCH][EMBP] bf16 embeddings
  ushort* hbuf;        // [2][BATCH][HID] bf16 double-buffered h
  float*  hfinal;      // [BATCH][HID] f32 final h
  int*    flags;       // [NWG] monotonic step counters
  const float* V[4];   // V_i,V_f,V_c,V_o  [HID][HID]
  const float* U[4];   // U_i,U_f,U_c,U_o  [EMB][HID]
  const float* bia[4]; // b_i,b_f,b_c,b_o  [HID]
  const float* Wd;     // [HID][3]
  const float* bd;     // [3]
  float* out;          // [BATCH][3]
};

// ---------------- prep: gather embeddings -> bf16, zero h0 and flags ----------------
__global__ void __launch_bounds__(256) prep(const int* __restrict__ text,
                                            const float* __restrict__ tab,
                                            ushort* __restrict__ xbf,
                                            ushort* __restrict__ hbuf,
                                            int* __restrict__ flags){
  const int tid = blockIdx.x * blockDim.x + threadIdx.x;
  const int nth = gridDim.x * blockDim.x;
  uint* hz = (uint*)hbuf;                       // zero hbuf[0]
  for (int i = tid; i < BATCH*HID/2; i += nth) hz[i] = 0u;
  if (tid < NWG) flags[tid] = 0;
  const int nch = SEQL*BATCH*(EMBP/8);
  for (int ch = tid; ch < nch; ch += nth){
    const int e8 = ch % (EMBP/8);
    const int sb = ch / (EMBP/8);               // sb = s*BATCH + b
    const int b  = sb & (BATCH-1);
    const int s  = sb >> 6;
    const int tok = text[b*SEQL + s];
    union { ushort u[8]; uint4 v; } o;
    #pragma unroll
    for (int j = 0; j < 8; j++){
      const int e = e8*8 + j;
      o.u[j] = f2bf(e < EMB ? tab[(size_t)tok*EMB + e] : 0.f);
    }
    *(uint4*)&xbf[(size_t)sb*EMBP + e8*8] = o.v;
  }
}

// ---- coherent-load software pipeline macros (V part) ----
#define VISSUE(c) { \
    const ushort* bp_ = hcur + (wave + 4*(c))*32 + qk; \
    _Pragma("unroll") \
    for (int m_ = 0; m_ < 4; m_++){ \
      const ushort* rp_ = bp_ + (size_t)(m_*16 + mrow)*HID; \
      asm volatile("global_load_dwordx2 %0, %2, off sc0 sc1\n\t" \
                   "global_load_dwordx2 %1, %2, off offset:32 sc0 sc1" \
                   : "=v"(afr[(c)&3][m_].lo), "=v"(afr[(c)&3][m_].hi) \
                   : "v"(rp_) : "memory"); \
    } }

#define VWAIT(n) { asm volatile("s_waitcnt vmcnt(" #n ")" ::: "memory"); \
                   __builtin_amdgcn_sched_barrier(0); }

#define VMFMA(c) { \
    _Pragma("unroll") \
    for (int m_ = 0; m_ < 4; m_++){ \
      Frag a_; \
      a_.uu[0] = afr[(c)&3][m_].lo[0]; a_.uu[1] = afr[(c)&3][m_].lo[1]; \
      a_.uu[2] = afr[(c)&3][m_].hi[0]; a_.uu[3] = afr[(c)&3][m_].hi[1]; \
      _Pragma("unroll") \
      for (int nt_ = 0; nt_ < 4; nt_++) \
        acc[m_][nt_] = __builtin_amdgcn_mfma_f32_16x16x32_bf16(a_.v, bfragV[c][nt_], acc[m_][nt_], 0, 0, 0); \
    } }

// ---------------- persistent LSTM scan ----------------
__global__ void __launch_bounds__(256, 1) lstm_scan(Params p){
  __shared__ float buffer[2][64][68];   // cross-wave partial sums [buf][col][batch(+pad)]
  __shared__ float cst[UNITS][BATCH];   // cell state (f32)
  __shared__ float bias_l[64];          // 4 gates x 16 units

  const int w    = blockIdx.x;
  const int tid  = threadIdx.x;
  const int wave = tid >> 6;
  const int lane = tid & 63;
  const int n0   = w * UNITS;
  const int mrow = lane & 15;           // A row / D col lane index
  const int qk   = ((lane >> 4) & 3) << 2;
  const int colg = n0 + mrow;
  const int uw   = (wave + 2) & 3;      // U-chunk offset: poller wave0 gets only 2 chunks
  const int nU   = (40 + uw < 42) ? 3 : 2;

  if (tid < 64) bias_l[tid] = p.bia[tid >> 4][n0 + (tid & 15)];
  for (int i = tid; i < UNITS*BATCH; i += 256) (&cst[0][0])[i] = 0.f;

  // ---- one-time: weights as bf16 MFMA B-fragments in registers ----
  // B-frag (16x16x32): lane holds B[k][n], n = mrow, k = (j>>2)*16 + qk + (j&3)
  short8 bfragV[8][4];
  #pragma unroll
  for (int kcl = 0; kcl < 8; kcl++){
    const int kc = wave + kcl*4;        // V K-chunks 0..31 round-robin across waves
    #pragma unroll
    for (int nt = 0; nt < 4; nt++){
      Frag fr;
      #pragma unroll
      for (int j = 0; j < 8; j++){
        const int krow = kc*32 + ((j >> 2) << 4) + qk + (j & 3);
        fr.u[j] = f2bf(p.V[nt][(size_t)krow*HID + colg]);
      }
      bfragV[kcl][nt] = fr.v;
    }
  }
  short8 bfragU[3][4];
  #pragma unroll
  for (int j3 = 0; j3 < 3; j3++){
    #pragma unroll
    for (int nt = 0; nt < 4; nt++){
      Frag fr;
      #pragma unroll
      for (int j = 0; j < 8; j++){
        float v = 0.f;
        if (j3 < nU){
          const int krow = (uw + 4*j3)*32 + ((j >> 2) << 4) + qk + (j & 3);
          if (krow < EMB) v = p.U[nt][(size_t)krow*HID + colg];
        }
        fr.u[j] = f2bf(v);
      }
      bfragU[j3][nt] = fr.v;
    }
  }
  __syncthreads();

  for (int t = 0; t < SEQL; t++){
    const ushort* __restrict__ xt = p.xbf + (size_t)t * (BATCH*EMBP);

    f32x4 acc[4][4];
    #pragma unroll
    for (int m = 0; m < 4; m++)
      #pragma unroll
      for (int nt = 0; nt < 4; nt++)
        acc[m][nt] = (f32x4){0.f, 0.f, 0.f, 0.f};

    // ---- x@U part (h-independent) — overlaps straggler publishes ----
    #pragma unroll
    for (int j3 = 0; j3 < 3; j3++){
      if (j3 < nU){
        const int kb = (uw + 4*j3)*32;
        Frag af[4];
        #pragma unroll
        for (int m = 0; m < 4; m++){
          const ushort* rp = xt + (size_t)(m*16 + mrow)*EMBP + kb + qk;
          uint2 lo = *(const uint2*)rp;
          uint2 hi = *(const uint2*)(rp + 16);
          af[m].uu[0] = lo.x; af[m].uu[1] = lo.y;
          af[m].uu[2] = hi.x; af[m].uu[3] = hi.y;
        }
        #pragma unroll
        for (int m = 0; m < 4; m++)
          #pragma unroll
          for (int nt = 0; nt < 4; nt++)
            acc[m][nt] = __builtin_amdgcn_mfma_f32_16x16x32_bf16(af[m].v, bfragU[j3][nt], acc[m][nt], 0, 0, 0);
      }
    }

    // ---- wait for h_t, then h@V with pipelined coherent loads ----
    if (t > 0){
      if (wave == 0){
        for (;;){
          int v = __hip_atomic_load(&p.flags[lane], __ATOMIC_RELAXED, __HIP_MEMORY_SCOPE_AGENT);
          if (__all(v >= t)) break;
          __builtin_amdgcn_s_sleep(1);
        }
      }
      __syncthreads();

      const ushort* __restrict__ hcur = p.hbuf + (size_t)(t & 1) * (BATCH*HID);
      AF afr[4][4];
      VISSUE(0) VISSUE(1) VISSUE(2) VISSUE(3)
      VWAIT(24) VMFMA(0) VISSUE(4)
      VWAIT(24) VMFMA(1) VISSUE(5)
      VWAIT(24) VMFMA(2) VISSUE(6)
      VWAIT(24) VMFMA(3) VISSUE(7)
      VWAIT(16) VMFMA(4)
      VWAIT(8)  VMFMA(5)
      VWAIT(8)  VMFMA(6)
      VWAIT(0)  VMFMA(7)
    }

    // ---- cross-wave reduction: buffer[0]=w0+w2, buffer[1]=w1+w3 ----
    const int fq = (lane >> 4) << 2;
    if (wave >= 2){
      #pragma unroll
      for (int m = 0; m < 4; m++)
        #pragma unroll
        for (int nt = 0; nt < 4; nt++)
          *(f32x4*)&buffer[wave-2][nt*16 + mrow][m*16 + fq] = acc[m][nt];
    }
    __syncthreads();
    if (wave < 2){
      #pragma unroll
      for (int m = 0; m < 4; m++)
        #pragma unroll
        for (int nt = 0; nt < 4; nt++){
          f32x4 o = *(f32x4*)&buffer[wave][nt*16 + mrow][m*16 + fq];
          o += acc[m][nt];
          *(f32x4*)&buffer[wave][nt*16 + mrow][m*16 + fq] = o;
        }
    }
    __syncthreads();

    // ---- elementwise LSTM update; publish h_{t+1} coherently ----
    const int eb = tid & 63;            // batch
    const int uq = tid >> 6;            // unit quad
    ushort* __restrict__ hnxt = p.hbuf + (size_t)((t+1) & 1) * (BATCH*HID);
    ushort hout[4]; float hfv[4];
    #pragma unroll
    for (int rr = 0; rr < 4; rr++){
      const int u = uq*4 + rr;
      float g0 = buffer[0][ 0+u][eb] + buffer[1][ 0+u][eb] + bias_l[ 0+u];
      float g1 = buffer[0][16+u][eb] + buffer[1][16+u][eb] + bias_l[16+u];
      float g2 = buffer[0][32+u][eb] + buffer[1][32+u][eb] + bias_l[32+u];
      float g3 = buffer[0][48+u][eb] + buffer[1][48+u][eb] + bias_l[48+u];
      float ig = 1.f/(1.f + __expf(-g0));
      float fg = 1.f/(1.f + __expf(-g1));
      float gg = 2.f/(1.f + __expf(-2.f*g2)) - 1.f;
      float og = 1.f/(1.f + __expf(-g3));
      float cv = fg * cst[u][eb] + ig * gg;
      cst[u][eb] = cv;
      float hv = og * (2.f/(1.f + __expf(-2.f*cv)) - 1.f);
      hout[rr] = f2bf(hv);
      hfv[rr] = hv;
    }
    {
      union { ushort u[4]; uint2v v; } pk;
      pk.u[0]=hout[0]; pk.u[1]=hout[1]; pk.u[2]=hout[2]; pk.u[3]=hout[3];
      ushort* sa = &hnxt[(size_t)eb*HID + n0 + uq*4];
      asm volatile("global_store_dwordx2 %0, %1, off sc0 sc1"
                   :: "v"(sa), "v"(pk.v) : "memory");
      if (t == SEQL-1){
        f32x4 fv; fv[0]=hfv[0]; fv[1]=hfv[1]; fv[2]=hfv[2]; fv[3]=hfv[3];
        float* fa = &p.hfinal[(size_t)eb*HID + n0 + uq*4];
        asm volatile("global_store_dwordx4 %0, %1, off sc0 sc1"
                     :: "v"(fa), "v"(fv) : "memory");
      }
    }
    asm volatile("s_waitcnt vmcnt(0)" ::: "memory");   // release: h visible at L3
    __syncthreads();
    if (tid == 0) __hip_atomic_store(&p.flags[w], t+1, __ATOMIC_RELAXED, __HIP_MEMORY_SCOPE_AGENT);
  }

  // ---- dense head: out[w] = h_n[w] @ Wd + bd (one WG per batch row) ----
  if (wave == 0){
    for (;;){
      int v = __hip_atomic_load(&p.flags[lane], __ATOMIC_RELAXED, __HIP_MEMORY_SCOPE_AGENT);
      if (__all(v >= SEQL)) break;
      __builtin_amdgcn_s_sleep(1);
    }
  }
  __syncthreads();
  asm volatile("" ::: "memory");        // keep hfinal loads below the poll

  float s0 = 0.f, s1 = 0.f, s2 = 0.f;
  const float* hf = p.hfinal + (size_t)w * HID;
  for (int k = tid; k < HID; k += 256){
    float hv = hf[k];
    s0 = fmaf(hv, p.Wd[k*3+0], s0);
    s1 = fmaf(hv, p.Wd[k*3+1], s1);
    s2 = fmaf(hv, p.Wd[k*3+2], s2);
  }
  float* red = &buffer[0][0][0];
  red[tid*3+0] = s0; red[tid*3+1] = s1; red[tid*3+2] = s2;
  __syncthreads();
  for (int off = 128; off > 0; off >>= 1){
    if (tid < off){
      red[tid*3+0] += red[(tid+off)*3+0];
      red[tid*3+1] += red[(tid+off)*3+1];
      red[tid*3+2] += red[(tid+off)*3+2];
    }
    __syncthreads();
  }
  if (tid < 3) p.out[w*3 + tid] = red[tid] + p.bd[tid];
}

// ---------------- host ----------------
extern "C" void kernel_launch(void* const* d_in, const int* in_sizes, int n_in,
                              void* d_out, int out_size, void* d_ws, size_t ws_size,
                              hipStream_t stream){
  const int*   text = (const int*)d_in[0];
  const float* tab  = (const float*)d_in[1];

  Params p;
  char* ws = (char*)d_ws;
  size_t off = 0;
  p.xbf    = (const ushort*)(ws + off); off += (size_t)SEQL*BATCH*EMBP*2;
  p.hbuf   = (ushort*)(ws + off);       off += (size_t)2*BATCH*HID*2;
  p.hfinal = (float*)(ws + off);        off += (size_t)BATCH*HID*4;
  p.flags  = (int*)(ws + off);          off += 256;

  for (int g = 0; g < 4; g++){
    p.U[g]   = (const float*)d_in[2+g];
    p.V[g]   = (const float*)d_in[6+g];
    p.bia[g] = (const float*)d_in[10+g];
  }
  p.Wd  = (const float*)d_in[14];
  p.bd  = (const float*)d_in[15];
  p.out = (float*)d_out;

  prep<<<1024, 256, 0, stream>>>(text, tab, (ushort*)p.xbf, p.hbuf, p.flags);
  lstm_scan<<<NWG, 256, 0, stream>>>(p);
}